// Round 1
// baseline (1638.202 us; speedup 1.0000x reference)
//
#include <hip/hip_runtime.h>

// DiagPooling: x[8,128,512,512] f32 -> out[8,1,513] f32
// out[b][u] = (1/(C*(H-|o|))) * sum_{c} sum_{j-i==o} x[b,c,i,j],  o = u-256
//
// Strategy: "diagonal walk". Each thread owns fixed diagonal offset(s); at row i
// it reads column i+o. Consecutive threads -> consecutive columns -> coalesced.
// Each thread keeps a scalar accumulator per owned diagonal (no LDS, no scatter),
// then one atomicAdd per (block, diagonal) into d_out. Finalize divides in place.

#define BB   8
#define CC   128
#define HH   512
#define WW   512
#define NOFF 513      // offsets -256..256
#define CPG  8        // channels per block
#define RPB  64       // rows per block
#define CG   (CC / CPG)  // 16
#define RG   (HH / RPB)  // 8

__global__ __launch_bounds__(256) void diag_sum(const float* __restrict__ x,
                                                float* __restrict__ acc) {
    const int t = threadIdx.x;          // 0..255
    const int blk = blockIdx.x;         // b*CG*RG + cg*RG + rg
    const int rg = blk & (RG - 1);
    const int cg = (blk >> 3) & (CG - 1);
    const int b  = blk >> 7;            // / (CG*RG) = /128
    const int r0 = rg * RPB;
    const bool last = (t == 255);

    float a0 = 0.f;   // diagonal o = t - 256  (output index t)
    float a1 = 0.f;   // diagonal o = t        (output index t + 256)
    float a2 = 0.f;   // diagonal o = 256      (output index 512, thread 255 only)

    for (int cch = 0; cch < CPG; ++cch) {
        const size_t planeOff = (size_t)(b * CC + cg * CPG + cch) * (size_t)(HH * WW);
        const float* __restrict__ row = x + planeOff + (size_t)r0 * WW;
        #pragma unroll 4
        for (int i = r0; i < r0 + RPB; ++i, row += WW) {
            const int j0 = i + t - 256;   // col for o = t-256; always < WW
            const int j1 = i + t;         // col for o = t;     always >= 0
            if (j0 >= 0) a0 += row[j0];
            if (j1 < WW) a1 += row[j1];
            if (last && i < 256) a2 += row[i + 256];
        }
    }

    float* accb = acc + b * NOFF;
    atomicAdd(accb + t,       a0);
    atomicAdd(accb + t + 256, a1);
    if (last) atomicAdd(accb + 512, a2);
}

__global__ void finalize(float* __restrict__ out) {
    const int idx = blockIdx.x * blockDim.x + threadIdx.x;
    if (idx >= BB * NOFF) return;
    const int u = idx % NOFF;
    const int o = u - 256;
    const int len = WW - (o < 0 ? -o : o);
    out[idx] = out[idx] / (float)(CC * len);
}

extern "C" void kernel_launch(void* const* d_in, const int* in_sizes, int n_in,
                              void* d_out, int out_size, void* d_ws, size_t ws_size,
                              hipStream_t stream) {
    const float* x = (const float*)d_in[0];
    float* out = (float*)d_out;

    // Harness poisons d_out with 0xAA before every timed launch; we accumulate
    // into it, so zero it first (async memset is graph-capture legal).
    hipMemsetAsync(out, 0, (size_t)out_size * sizeof(float), stream);

    diag_sum<<<dim3(BB * CG * RG), dim3(256), 0, stream>>>(x, out);
    finalize<<<dim3((BB * NOFF + 255) / 256), dim3(256), 0, stream>>>(out);
}